// Round 14
// baseline (220.916 us; speedup 1.0000x reference)
//
#include <hip/hip_runtime.h>

typedef __attribute__((ext_vector_type(8))) short bf16x8;
typedef __attribute__((ext_vector_type(4))) float f32x4;
typedef unsigned short u16;
typedef unsigned int u32;

#define NN 8192
#define FD 256

__device__ __forceinline__ u16 f2bf(float f) {
  union { float f; unsigned u; } v; v.f = f;
  unsigned r = v.u + 0x7FFF + ((v.u >> 16) & 1);
  return (u16)(r >> 16);
}

__device__ __forceinline__ bf16x8 ldcvt8(const float* __restrict__ p) {
  f32x4 x0 = *(const f32x4*)p;
  f32x4 x1 = *(const f32x4*)(p + 4);
  bf16x8 t;
  t[0] = (short)f2bf(x0[0]); t[1] = (short)f2bf(x0[1]);
  t[2] = (short)f2bf(x0[2]); t[3] = (short)f2bf(x0[3]);
  t[4] = (short)f2bf(x1[0]); t[5] = (short)f2bf(x1[1]);
  t[6] = (short)f2bf(x1[2]); t[7] = (short)f2bf(x1[3]);
  return t;
}

__device__ __forceinline__ void gl16(const void* g, void* l) {
  __builtin_amdgcn_global_load_lds((const __attribute__((address_space(1))) u32*)g,
                                   (__attribute__((address_space(3))) u32*)l, 16, 0, 0);
}

// ---- K0: zero src/dst (64 KB) ----
__global__ __launch_bounds__(256) void k_zero(float* __restrict__ p) {
  int g = (blockIdx.x * 256 + threadIdx.x) * 4;
  f32x4 z = {0.f, 0.f, 0.f, 0.f};
  *(f32x4*)(p + g) = z;
}

// ---- K0b: adj (268 MB f32) -> bitmask (8 MB). Pure stream, no barriers. ----
// word g covers adj[g*32 .. g*32+32); bit e = (adj[g*32+e] != 0)
__global__ __launch_bounds__(256) void k_bits(const float* __restrict__ adj,
                                              u32* __restrict__ bits) {
  size_t g = (size_t)blockIdx.x * 256 + threadIdx.x;
  const float* p = adj + g * 32;
  u32 w = 0;
#pragma unroll
  for (int v = 0; v < 8; v++) {
    f32x4 x = *(const f32x4*)(p + v * 4);
    w |= (x[0] != 0.f ? 1u : 0u) << (v * 4);
    w |= (x[1] != 0.f ? 1u : 0u) << (v * 4 + 1);
    w |= (x[2] != 0.f ? 1u : 0u) << (v * 4 + 2);
    w |= (x[3] != 0.f ? 1u : 0u) << (v * 4 + 3);
  }
  bits[g] = w;
}

// ---- K1: Wh = h @ W -> whT[c][r] (bf16), fused src/dst dot + atomicAdd ----
__global__ __launch_bounds__(256) void k_wh(const float* __restrict__ h,
                                            const float* __restrict__ W,
                                            const float* __restrict__ a,
                                            u16* __restrict__ whT,
                                            float* __restrict__ src,
                                            float* __restrict__ dst) {
  int tid = threadIdx.x;
  int lane = tid & 63;
  int wv = tid >> 6;
  int r0 = blockIdx.x * 64 + (wv >> 1) * 32;
  int c0 = blockIdx.y * 64 + (wv & 1) * 32;
  int lr = lane & 15;
  int q = lane >> 4;

  f32x4 acc[2][2] = {};
  for (int kk = 0; kk < FD; kk += 32) {
    int kb = kk + q * 8;
    bf16x8 av[2], bv[2];
#pragma unroll
    for (int m = 0; m < 2; m++)
      av[m] = ldcvt8(h + (size_t)(r0 + m * 16 + lr) * FD + kb);
#pragma unroll
    for (int n = 0; n < 2; n++) {
      int col = c0 + n * 16 + lr;
      const float* p = W + (size_t)kb * FD + col;
      bf16x8 t;
#pragma unroll
      for (int e = 0; e < 8; e++) t[e] = (short)f2bf(p[(size_t)e * FD]);
      bv[n] = t;
    }
#pragma unroll
    for (int m = 0; m < 2; m++)
#pragma unroll
      for (int n = 0; n < 2; n++)
        acc[m][n] = __builtin_amdgcn_mfma_f32_16x16x32_bf16(av[m], bv[n], acc[m][n], 0, 0, 0);
  }
#pragma unroll
  for (int m = 0; m < 2; m++)
#pragma unroll
    for (int n = 0; n < 2; n++) {
      int gc = c0 + n * 16 + lr;
      int gr = r0 + m * 16 + q * 4;
      ushort4 st;
      st.x = f2bf(acc[m][n][0]);
      st.y = f2bf(acc[m][n][1]);
      st.z = f2bf(acc[m][n][2]);
      st.w = f2bf(acc[m][n][3]);
      *(ushort4*)(whT + (size_t)gc * NN + gr) = st;
    }
  float aA0 = a[c0 + lr], aA1 = a[c0 + 16 + lr];
  float aB0 = a[256 + c0 + lr], aB1 = a[256 + c0 + 16 + lr];
#pragma unroll
  for (int m = 0; m < 2; m++)
#pragma unroll
    for (int j = 0; j < 4; j++) {
      float s1 = acc[m][0][j] * aA0 + acc[m][1][j] * aA1;
      float s2 = acc[m][0][j] * aB0 + acc[m][1][j] * aB1;
#pragma unroll
      for (int sh = 1; sh < 16; sh <<= 1) {
        s1 += __shfl_xor(s1, sh);
        s2 += __shfl_xor(s2, sh);
      }
      if (lr == 0) {
        int row = r0 + m * 16 + q * 4 + j;
        atomicAdd(&src[row], s1);
        atomicAdd(&dst[row], s2);
      }
    }
}

// ---- K2: attention from BITS. BM=256 x JS=8, 256 blocks (1/CU) x 512 thr.
// Zero adj traffic: P decoded from 8MB bitmask (L2). whT tile staged per step
// via pre-swizzled global_load_lds ring (R7/R13-proven conflict-free). P into
// pitch-40 double buffer. Counted vmcnt(4)+lgkm barrier; &31 wrap keeps issue
// counts constant. Traffic: bits 8MB + whT 128MB(L2) + stores 64MB.
__global__ __launch_bounds__(512, 2) void k_att(const u32* __restrict__ bits,
                                                const u16* __restrict__ whT,
                                                const float* __restrict__ src,
                                                const float* __restrict__ dst,
                                                float* __restrict__ hpp,
                                                float* __restrict__ lgp) {
  __shared__ u16 wtile[4][8192];     // 64 KB whT ring
  __shared__ u16 pbuf[2][10240];     // 40 KB P double buffer (pitch 40)
  __shared__ float dst_lds[1024];    // 4 KB

  const int tid = threadIdx.x;
  const int lane = tid & 63;
  const int w = tid >> 6;
  const int lr = lane & 15;
  const int q = lane >> 4;
  const int rg = w >> 1;            // row-group: 64 rows
  const int ch = w & 1;             // c-half: 128 cols
  const int bid = blockIdx.x;
  const int jh = bid & 7;
  const int i0 = (bid >> 3) * 256;
  const int jb = jh * 1024;

  // P-gen: thread -> row pr (0..255), 16 j at pj
  const int pr = tid >> 1;
  const int pj = (tid & 1) * 16;
  const u32* bp = bits + (size_t)(i0 + pr) * 256 + jh * 32;
  const float srcv = src[i0 + pr];

  // gl_lds source pre-swizzle (R13-proven)
  const int gcr = lane >> 2;
  const int jsw = (lane & 3) ^ (gcr & 3);
  const u16* wsrc0 = whT + (size_t)(w * 32 + gcr) * NN + jb + jsw * 8;
  const u16* wsrc1 = wsrc0 + (size_t)16 * NN;

  f32x4 acc[4][8] = {};
  float lsum = 0.f;
  u32 wE, wO;

#define GLDS(T)                                                              \
  {                                                                          \
    int _s = (T) & 3;                                                        \
    gl16(wsrc0 + (size_t)((T) & 31) * 32, &wtile[_s][w * 1024]);             \
    gl16(wsrc1 + (size_t)((T) & 31) * 32, &wtile[_s][w * 1024 + 512]);       \
  }
#define BITLD(T, R) R = bp[(T) & 31];
#define PGEN(T, R, PB)                                                       \
  {                                                                          \
    u32 wv = (R) >> pj;                                                      \
    _Pragma("unroll") for (int v = 0; v < 4; v++) {                          \
      f32x4 dv = *(const f32x4*)&dst_lds[((T) & 31) * 32 + pj + v * 4];      \
      ushort4 st;                                                            \
      { float x = srcv + dv[0]; x = fmaxf(x, 0.2f * x); float p = ((wv >> (v * 4)) & 1) ? __expf(x) : 0.f; lsum += p; st.x = f2bf(p); } \
      { float x = srcv + dv[1]; x = fmaxf(x, 0.2f * x); float p = ((wv >> (v * 4 + 1)) & 1) ? __expf(x) : 0.f; lsum += p; st.y = f2bf(p); } \
      { float x = srcv + dv[2]; x = fmaxf(x, 0.2f * x); float p = ((wv >> (v * 4 + 2)) & 1) ? __expf(x) : 0.f; lsum += p; st.z = f2bf(p); } \
      { float x = srcv + dv[3]; x = fmaxf(x, 0.2f * x); float p = ((wv >> (v * 4 + 3)) & 1) ? __expf(x) : 0.f; lsum += p; st.w = f2bf(p); } \
      *(ushort4*)&pbuf[PB][pr * 40 + pj + v * 4] = st;                       \
    }                                                                        \
  }
#define MSTEP(T, PB)                                                         \
  {                                                                          \
    const u16* bb = &wtile[(T) & 3][0];                                      \
    const u16* pp = &pbuf[PB][0];                                            \
    bf16x8 bfs[8];                                                           \
    _Pragma("unroll") for (int ct = 0; ct < 8; ct++)                         \
      bfs[ct] = *(const bf16x8*)&bb[(ch * 4 + (ct >> 1)) * 1024 + (ct & 1) * 512 + lr * 32 + (q ^ (lr & 3)) * 8]; \
    __builtin_amdgcn_s_setprio(1);                                           \
    _Pragma("unroll") for (int rt = 0; rt < 4; rt++) {                       \
      bf16x8 af = *(const bf16x8*)&pp[(rg * 64 + rt * 16 + lr) * 40 + q * 8]; \
      _Pragma("unroll") for (int ct = 0; ct < 8; ct++)                       \
        acc[rt][ct] = __builtin_amdgcn_mfma_f32_16x16x32_bf16(af, bfs[ct], acc[rt][ct], 0, 0, 0); \
    }                                                                        \
    __builtin_amdgcn_s_setprio(0);                                           \
  }
#define ENDBAR asm volatile("s_waitcnt vmcnt(4) lgkmcnt(0)\n\ts_barrier" ::: "memory")

  // prologue
  if (tid < 256) {
    f32x4 v = *(const f32x4*)(dst + jb + tid * 4);
    *(f32x4*)&dst_lds[tid * 4] = v;
  }
  GLDS(0);
  GLDS(1);
  BITLD(0, wE);
  BITLD(1, wO);
  __syncthreads();              // full drain: dst_lds + tiles 0,1 + bits 0,1
  PGEN(0, wE, 0);
  BITLD(2, wE);
  asm volatile("s_waitcnt lgkmcnt(0)\n\ts_barrier" ::: "memory");  // P(0) visible

  for (int t = 0; t < 32; t += 2) {
    GLDS(t + 2);
    PGEN(t + 1, wO, 1);
    BITLD(t + 3, wO);
    MSTEP(t, 0);
    ENDBAR;
    GLDS(t + 3);
    PGEN(t + 2, wE, 0);
    BITLD(t + 4, wE);
    MSTEP(t + 1, 1);
    ENDBAR;
  }
#undef GLDS
#undef BITLD
#undef PGEN
#undef MSTEP
#undef ENDBAR

  // row-sum partial: 2 threads per row
  lsum += __shfl_xor(lsum, 1);
  if ((lane & 1) == 0) lgp[jh * NN + i0 + pr] = lsum;

  // partial h' plain stores: hpp slice jh
  float* hs = hpp + (size_t)jh * NN * FD;
#pragma unroll
  for (int rt = 0; rt < 4; rt++)
#pragma unroll
    for (int ct = 0; ct < 8; ct++) {
      int c = ch * 128 + ct * 16 + lr;
#pragma unroll
      for (int j = 0; j < 4; j++) {
        int row = i0 + rg * 64 + rt * 16 + q * 4 + j;
        hs[(size_t)row * FD + c] = acc[rt][ct][j];
      }
    }
}

// ---- K3: sum 8 partials, normalize, cast bf16 (hpb aliases whT) ----
__global__ __launch_bounds__(256) void k_norm(const float* __restrict__ hpp,
                                              const float* __restrict__ lgp,
                                              u16* __restrict__ hpb) {
  int gid = blockIdx.x * 256 + threadIdx.x;
  int idx = gid * 4;
  int row = idx >> 8;
  f32x4 s = {0.f, 0.f, 0.f, 0.f};
  float l = 0.f;
#pragma unroll
  for (int jh = 0; jh < 8; jh++) {
    s += *(const f32x4*)(hpp + (size_t)jh * NN * FD + idx);
    l += lgp[jh * NN + row];
  }
  float inv = 1.0f / l;
  ushort4 st;
  st.x = f2bf(s[0] * inv);
  st.y = f2bf(s[1] * inv);
  st.z = f2bf(s[2] * inv);
  st.w = f2bf(s[3] * inv);
  *(ushort4*)(hpb + idx) = st;
}

// ---- K4: fused GRUCell (h, w_ih, w_hh cast f32->bf16 inline) ----
__global__ __launch_bounds__(256) void k_gru(const u16* __restrict__ hpb,
                                             const float* __restrict__ h,
                                             const float* __restrict__ wih,
                                             const float* __restrict__ whh,
                                             const float* __restrict__ bih,
                                             const float* __restrict__ bhh,
                                             float* __restrict__ out) {
  int tid = threadIdx.x;
  int lane = tid & 63;
  int wv = tid >> 6;
  int i0 = blockIdx.x * 32;
  int lr = lane & 15;
  int q = lane >> 4;
  int c = blockIdx.y * 64 + wv * 16 + lr;
  f32x4 gi[3][2] = {};
  f32x4 gh[3][2] = {};
  for (int kk = 0; kk < FD; kk += 32) {
    int kb = kk + q * 8;
    bf16x8 ap[2], ah[2], bi[3], bh[3];
#pragma unroll
    for (int m = 0; m < 2; m++) {
      ap[m] = *(const bf16x8*)(hpb + (size_t)(i0 + m * 16 + lr) * FD + kb);
      ah[m] = ldcvt8(h + (size_t)(i0 + m * 16 + lr) * FD + kb);
    }
#pragma unroll
    for (int g = 0; g < 3; g++) {
      bi[g] = ldcvt8(wih + (size_t)(g * 256 + c) * FD + kb);
      bh[g] = ldcvt8(whh + (size_t)(g * 256 + c) * FD + kb);
    }
#pragma unroll
    for (int g = 0; g < 3; g++)
#pragma unroll
      for (int m = 0; m < 2; m++) {
        gi[g][m] = __builtin_amdgcn_mfma_f32_16x16x32_bf16(ap[m], bi[g], gi[g][m], 0, 0, 0);
        gh[g][m] = __builtin_amdgcn_mfma_f32_16x16x32_bf16(ah[m], bh[g], gh[g][m], 0, 0, 0);
      }
  }
  float bir = bih[c], biz = bih[256 + c], bin = bih[512 + c];
  float bhr = bhh[c], bhz = bhh[256 + c], bhn = bhh[512 + c];
#pragma unroll
  for (int m = 0; m < 2; m++)
#pragma unroll
    for (int j = 0; j < 4; j++) {
      int row = i0 + m * 16 + q * 4 + j;
      float rv = gi[0][m][j] + bir + gh[0][m][j] + bhr;
      float zv = gi[1][m][j] + biz + gh[1][m][j] + bhz;
      float r = 1.f / (1.f + __expf(-rv));
      float z = 1.f / (1.f + __expf(-zv));
      float nx = gi[2][m][j] + bin + r * (gh[2][m][j] + bhn);
      float n = 1.f - 2.f / (__expf(2.f * nx) + 1.f);
      float hv = h[(size_t)row * FD + c];
      out[(size_t)row * FD + c] = (1.f - z) * n + z * hv;
    }
}

extern "C" void kernel_launch(void* const* d_in, const int* in_sizes, int n_in,
                              void* d_out, int out_size, void* d_ws, size_t ws_size,
                              hipStream_t stream) {
  const float* h   = (const float*)d_in[0];
  const float* adj = (const float*)d_in[1];
  const float* W   = (const float*)d_in[2];
  const float* a   = (const float*)d_in[3];
  const float* wih = (const float*)d_in[4];
  const float* whh = (const float*)d_in[5];
  const float* bih = (const float*)d_in[6];
  const float* bhh = (const float*)d_in[7];
  float* out = (float*)d_out;

  // ws layout (~80 MB; harness poison fill shows ws ~1 GB):
  char* ws = (char*)d_ws;
  u16* whT   = (u16*)(ws);                   // [0, 4 MB) Wh^T bf16; aliased by hpb
  u16* hpb   = (u16*)(ws);                   //   alias
  float* hpp = (float*)(ws + 4194304);       // [4 MB, 68 MB) 8 x h'-partials f32
  float* lgp = (float*)(ws + 71303168);      // 256 KB row-sum partials
  float* srcv = (float*)(ws + 71565312);     // 32 KB
  float* dstv = (float*)(ws + 71598080);     // 32 KB
  u32* bits  = (u32*)(ws + 71630848);        // 8 MB adj bitmask
  (void)ws_size;

  k_zero<<<16, 256, 0, stream>>>(srcv);      // src+dst 64 KB contiguous
  k_bits<<<8192, 256, 0, stream>>>(adj, bits);
  k_wh<<<dim3(128, 4), 256, 0, stream>>>(h, W, a, whT, srcv, dstv);
  k_att<<<256, 512, 0, stream>>>(bits, whT, srcv, dstv, hpp, lgp);
  k_norm<<<2048, 256, 0, stream>>>(hpp, lgp, hpb);
  k_gru<<<dim3(256, 4), 256, 0, stream>>>(hpb, h, wih, whh, bih, bhh, out);
}

// Round 15
// 208.140 us; speedup vs baseline: 1.0614x; 1.0614x over previous
//
#include <hip/hip_runtime.h>

typedef __attribute__((ext_vector_type(8))) short bf16x8;
typedef __attribute__((ext_vector_type(4))) float f32x4;
typedef unsigned short u16;
typedef unsigned int u32;

#define NN 8192
#define FD 256

__device__ __forceinline__ u16 f2bf(float f) {
  union { float f; unsigned u; } v; v.f = f;
  unsigned r = v.u + 0x7FFF + ((v.u >> 16) & 1);
  return (u16)(r >> 16);
}

__device__ __forceinline__ bf16x8 ldcvt8(const float* __restrict__ p) {
  f32x4 x0 = *(const f32x4*)p;
  f32x4 x1 = *(const f32x4*)(p + 4);
  bf16x8 t;
  t[0] = (short)f2bf(x0[0]); t[1] = (short)f2bf(x0[1]);
  t[2] = (short)f2bf(x0[2]); t[3] = (short)f2bf(x0[3]);
  t[4] = (short)f2bf(x1[0]); t[5] = (short)f2bf(x1[1]);
  t[6] = (short)f2bf(x1[2]); t[7] = (short)f2bf(x1[3]);
  return t;
}

__device__ __forceinline__ void gl16(const void* g, void* l) {
  __builtin_amdgcn_global_load_lds((const __attribute__((address_space(1))) u32*)g,
                                   (__attribute__((address_space(3))) u32*)l, 16, 0, 0);
}

// ---- K0: zero src/dst (64 KB) ----
__global__ __launch_bounds__(256) void k_zero(float* __restrict__ p) {
  int g = (blockIdx.x * 256 + threadIdx.x) * 4;
  f32x4 z = {0.f, 0.f, 0.f, 0.f};
  *(f32x4*)(p + g) = z;
}

// ---- K1: Wh = h @ W -> whT[c][r] (bf16), fused src/dst dot + atomicAdd ----
__global__ __launch_bounds__(256) void k_wh(const float* __restrict__ h,
                                            const float* __restrict__ W,
                                            const float* __restrict__ a,
                                            u16* __restrict__ whT,
                                            float* __restrict__ src,
                                            float* __restrict__ dst) {
  int tid = threadIdx.x;
  int lane = tid & 63;
  int wv = tid >> 6;
  int r0 = blockIdx.x * 64 + (wv >> 1) * 32;
  int c0 = blockIdx.y * 64 + (wv & 1) * 32;
  int lr = lane & 15;
  int q = lane >> 4;

  f32x4 acc[2][2] = {};
  for (int kk = 0; kk < FD; kk += 32) {
    int kb = kk + q * 8;
    bf16x8 av[2], bv[2];
#pragma unroll
    for (int m = 0; m < 2; m++)
      av[m] = ldcvt8(h + (size_t)(r0 + m * 16 + lr) * FD + kb);
#pragma unroll
    for (int n = 0; n < 2; n++) {
      int col = c0 + n * 16 + lr;
      const float* p = W + (size_t)kb * FD + col;
      bf16x8 t;
#pragma unroll
      for (int e = 0; e < 8; e++) t[e] = (short)f2bf(p[(size_t)e * FD]);
      bv[n] = t;
    }
#pragma unroll
    for (int m = 0; m < 2; m++)
#pragma unroll
      for (int n = 0; n < 2; n++)
        acc[m][n] = __builtin_amdgcn_mfma_f32_16x16x32_bf16(av[m], bv[n], acc[m][n], 0, 0, 0);
  }
#pragma unroll
  for (int m = 0; m < 2; m++)
#pragma unroll
    for (int n = 0; n < 2; n++) {
      int gc = c0 + n * 16 + lr;
      int gr = r0 + m * 16 + q * 4;
      ushort4 st;
      st.x = f2bf(acc[m][n][0]);
      st.y = f2bf(acc[m][n][1]);
      st.z = f2bf(acc[m][n][2]);
      st.w = f2bf(acc[m][n][3]);
      *(ushort4*)(whT + (size_t)gc * NN + gr) = st;
    }
  float aA0 = a[c0 + lr], aA1 = a[c0 + 16 + lr];
  float aB0 = a[256 + c0 + lr], aB1 = a[256 + c0 + 16 + lr];
#pragma unroll
  for (int m = 0; m < 2; m++)
#pragma unroll
    for (int j = 0; j < 4; j++) {
      float s1 = acc[m][0][j] * aA0 + acc[m][1][j] * aA1;
      float s2 = acc[m][0][j] * aB0 + acc[m][1][j] * aB1;
#pragma unroll
      for (int sh = 1; sh < 16; sh <<= 1) {
        s1 += __shfl_xor(s1, sh);
        s2 += __shfl_xor(s2, sh);
      }
      if (lr == 0) {
        int row = r0 + m * 16 + q * 4 + j;
        atomicAdd(&src[row], s1);
        atomicAdd(&dst[row], s2);
      }
    }
}

// ---- K2: attention, BM=256 x JS=8. 256 blocks (1/CU) x 512 thr (8 waves).
// __launch_bounds__(512,1): 256-VGPR cap so acc[4][8] (128 f32, unified
// VGPR/AGPR file) stays in registers — the (512,2) variant capped at 128 VGPR
// and spilled the accumulators to scratch (R13/R14's hidden ~5x tax; LDS
// 108KB already forces 1 block/CU, so (512,2) bought nothing).
// whT tile staged per step via pre-swizzled global_load_lds ring; P into
// pitch-40 double buffer; counted vmcnt(10)+lgkm barrier; &31 wraparound.
__global__ __launch_bounds__(512, 1) void k_att(const float* __restrict__ adj,
                                                const u16* __restrict__ whT,
                                                const float* __restrict__ src,
                                                const float* __restrict__ dst,
                                                float* __restrict__ hpp,
                                                float* __restrict__ lgp) {
  __shared__ u16 wtile[4][8192];     // 64 KB whT ring
  __shared__ u16 pbuf[2][10240];     // 40 KB P double buffer (pitch 40)
  __shared__ float dst_lds[1024];    // 4 KB

  const int tid = threadIdx.x;
  const int lane = tid & 63;
  const int w = tid >> 6;
  const int lr = lane & 15;
  const int q = lane >> 4;
  const int rg = w >> 1;            // row-group: 64 rows
  const int ch = w & 1;             // c-half: 128 cols
  const int bid = blockIdx.x;
  const int jh = bid & 7;
  const int i0 = (bid >> 3) * 256;
  const int jb = jh * 1024;

  // P-gen: thread -> row pr (0..255), 16 j at pj
  const int pr = tid >> 1;
  const int pj = (tid & 1) * 16;
  const float* adjP = adj + (size_t)(i0 + pr) * NN + jb + pj;
  const float srcv = src[i0 + pr];

  // gl_lds source pre-swizzle: instr k covers c = w*32 + k*16 + (lane>>2),
  // LDS 16B slot s = lane&3 holds global j-slot s ^ ((lane>>2)&3)
  const int gcr = lane >> 2;
  const int jsw = (lane & 3) ^ (gcr & 3);
  const u16* wsrc0 = whT + (size_t)(w * 32 + gcr) * NN + jb + jsw * 8;
  const u16* wsrc1 = wsrc0 + (size_t)16 * NN;

  f32x4 acc[4][8] = {};
  float lsum = 0.f;
  f32x4 arE[4], arO[4];

#define GLDS(T)                                                              \
  {                                                                          \
    int _s = (T) & 3;                                                        \
    gl16(wsrc0 + (size_t)((T) & 31) * 32, &wtile[_s][w * 1024]);             \
    gl16(wsrc1 + (size_t)((T) & 31) * 32, &wtile[_s][w * 1024 + 512]);       \
  }
#define ALD(T, AR)                                                           \
  { _Pragma("unroll") for (int v = 0; v < 4; v++)                            \
      AR[v] = *(const f32x4*)(adjP + (size_t)((T) & 31) * 32 + v * 4); }
#define PGEN(T, AR, PB)                                                      \
  {                                                                          \
    _Pragma("unroll") for (int v = 0; v < 4; v++) {                          \
      f32x4 dv = *(const f32x4*)&dst_lds[((T) & 31) * 32 + pj + v * 4];      \
      ushort4 st;                                                            \
      { float x = srcv + dv[0]; x = fmaxf(x, 0.2f * x); float p = AR[v][0] * __expf(x); lsum += p; st.x = f2bf(p); } \
      { float x = srcv + dv[1]; x = fmaxf(x, 0.2f * x); float p = AR[v][1] * __expf(x); lsum += p; st.y = f2bf(p); } \
      { float x = srcv + dv[2]; x = fmaxf(x, 0.2f * x); float p = AR[v][2] * __expf(x); lsum += p; st.z = f2bf(p); } \
      { float x = srcv + dv[3]; x = fmaxf(x, 0.2f * x); float p = AR[v][3] * __expf(x); lsum += p; st.w = f2bf(p); } \
      *(ushort4*)&pbuf[PB][pr * 40 + pj + v * 4] = st;                       \
    }                                                                        \
  }
#define MSTEP(T, PB)                                                         \
  {                                                                          \
    const u16* bb = &wtile[(T) & 3][0];                                      \
    const u16* pp = &pbuf[PB][0];                                            \
    bf16x8 bfs[8];                                                           \
    _Pragma("unroll") for (int ct = 0; ct < 8; ct++)                         \
      bfs[ct] = *(const bf16x8*)&bb[(ch * 4 + (ct >> 1)) * 1024 + (ct & 1) * 512 + lr * 32 + (q ^ (lr & 3)) * 8]; \
    __builtin_amdgcn_s_setprio(1);                                           \
    _Pragma("unroll") for (int rt = 0; rt < 4; rt++) {                       \
      bf16x8 af = *(const bf16x8*)&pp[(rg * 64 + rt * 16 + lr) * 40 + q * 8]; \
      _Pragma("unroll") for (int ct = 0; ct < 8; ct++)                       \
        acc[rt][ct] = __builtin_amdgcn_mfma_f32_16x16x32_bf16(af, bfs[ct], acc[rt][ct], 0, 0, 0); \
    }                                                                        \
    __builtin_amdgcn_s_setprio(0);                                           \
  }
#define ENDBAR asm volatile("s_waitcnt vmcnt(10) lgkmcnt(0)\n\ts_barrier" ::: "memory")

  // prologue
  if (tid < 256) {
    f32x4 v = *(const f32x4*)(dst + jb + tid * 4);
    *(f32x4*)&dst_lds[tid * 4] = v;
  }
  GLDS(0);
  GLDS(1);
  ALD(0, arE);
  ALD(1, arO);
  __syncthreads();              // full drain: dst_lds + tiles 0,1 + adj 0,1 ready
  PGEN(0, arE, 0);
  ALD(2, arE);
  asm volatile("s_waitcnt lgkmcnt(0)\n\ts_barrier" ::: "memory");  // P(0) visible

  for (int t = 0; t < 32; t += 2) {
    // body t (even): MFMA step t, stage P(t+1), tile t+2, adj t+3
    GLDS(t + 2);
    PGEN(t + 1, arO, 1);
    ALD(t + 3, arO);
    MSTEP(t, 0);
    ENDBAR;
    // body t+1 (odd): MFMA step t+1, stage P(t+2), tile t+3, adj t+4
    GLDS(t + 3);
    PGEN(t + 2, arE, 0);
    ALD(t + 4, arE);
    MSTEP(t + 1, 1);
    ENDBAR;
  }
#undef GLDS
#undef ALD
#undef PGEN
#undef MSTEP
#undef ENDBAR

  // row-sum partial: 2 threads per row
  lsum += __shfl_xor(lsum, 1);
  if ((lane & 1) == 0) lgp[jh * NN + i0 + pr] = lsum;

  // partial h' plain stores: hpp slice jh
  float* hs = hpp + (size_t)jh * NN * FD;
#pragma unroll
  for (int rt = 0; rt < 4; rt++)
#pragma unroll
    for (int ct = 0; ct < 8; ct++) {
      int c = ch * 128 + ct * 16 + lr;
#pragma unroll
      for (int j = 0; j < 4; j++) {
        int row = i0 + rg * 64 + rt * 16 + q * 4 + j;
        hs[(size_t)row * FD + c] = acc[rt][ct][j];
      }
    }
}

// ---- K3: sum 8 partials, normalize by row-sum, cast bf16 (hpb aliases whT) ----
__global__ __launch_bounds__(256) void k_norm(const float* __restrict__ hpp,
                                              const float* __restrict__ lgp,
                                              u16* __restrict__ hpb) {
  int gid = blockIdx.x * 256 + threadIdx.x;
  int idx = gid * 4;
  int row = idx >> 8;
  f32x4 s = {0.f, 0.f, 0.f, 0.f};
  float l = 0.f;
#pragma unroll
  for (int jh = 0; jh < 8; jh++) {
    s += *(const f32x4*)(hpp + (size_t)jh * NN * FD + idx);
    l += lgp[jh * NN + row];
  }
  float inv = 1.0f / l;
  ushort4 st;
  st.x = f2bf(s[0] * inv);
  st.y = f2bf(s[1] * inv);
  st.z = f2bf(s[2] * inv);
  st.w = f2bf(s[3] * inv);
  *(ushort4*)(hpb + idx) = st;
}

// ---- K4: fused GRUCell (h, w_ih, w_hh cast f32->bf16 inline) ----
__global__ __launch_bounds__(256) void k_gru(const u16* __restrict__ hpb,
                                             const float* __restrict__ h,
                                             const float* __restrict__ wih,
                                             const float* __restrict__ whh,
                                             const float* __restrict__ bih,
                                             const float* __restrict__ bhh,
                                             float* __restrict__ out) {
  int tid = threadIdx.x;
  int lane = tid & 63;
  int wv = tid >> 6;
  int i0 = blockIdx.x * 32;
  int lr = lane & 15;
  int q = lane >> 4;
  int c = blockIdx.y * 64 + wv * 16 + lr;
  f32x4 gi[3][2] = {};
  f32x4 gh[3][2] = {};
  for (int kk = 0; kk < FD; kk += 32) {
    int kb = kk + q * 8;
    bf16x8 ap[2], ah[2], bi[3], bh[3];
#pragma unroll
    for (int m = 0; m < 2; m++) {
      ap[m] = *(const bf16x8*)(hpb + (size_t)(i0 + m * 16 + lr) * FD + kb);
      ah[m] = ldcvt8(h + (size_t)(i0 + m * 16 + lr) * FD + kb);
    }
#pragma unroll
    for (int g = 0; g < 3; g++) {
      bi[g] = ldcvt8(wih + (size_t)(g * 256 + c) * FD + kb);
      bh[g] = ldcvt8(whh + (size_t)(g * 256 + c) * FD + kb);
    }
#pragma unroll
    for (int g = 0; g < 3; g++)
#pragma unroll
      for (int m = 0; m < 2; m++) {
        gi[g][m] = __builtin_amdgcn_mfma_f32_16x16x32_bf16(ap[m], bi[g], gi[g][m], 0, 0, 0);
        gh[g][m] = __builtin_amdgcn_mfma_f32_16x16x32_bf16(ah[m], bh[g], gh[g][m], 0, 0, 0);
      }
  }
  float bir = bih[c], biz = bih[256 + c], bin = bih[512 + c];
  float bhr = bhh[c], bhz = bhh[256 + c], bhn = bhh[512 + c];
#pragma unroll
  for (int m = 0; m < 2; m++)
#pragma unroll
    for (int j = 0; j < 4; j++) {
      int row = i0 + m * 16 + q * 4 + j;
      float rv = gi[0][m][j] + bir + gh[0][m][j] + bhr;
      float zv = gi[1][m][j] + biz + gh[1][m][j] + bhz;
      float r = 1.f / (1.f + __expf(-rv));
      float z = 1.f / (1.f + __expf(-zv));
      float nx = gi[2][m][j] + bin + r * (gh[2][m][j] + bhn);
      float n = 1.f - 2.f / (__expf(2.f * nx) + 1.f);
      float hv = h[(size_t)row * FD + c];
      out[(size_t)row * FD + c] = (1.f - z) * n + z * hv;
    }
}

extern "C" void kernel_launch(void* const* d_in, const int* in_sizes, int n_in,
                              void* d_out, int out_size, void* d_ws, size_t ws_size,
                              hipStream_t stream) {
  const float* h   = (const float*)d_in[0];
  const float* adj = (const float*)d_in[1];
  const float* W   = (const float*)d_in[2];
  const float* a   = (const float*)d_in[3];
  const float* wih = (const float*)d_in[4];
  const float* whh = (const float*)d_in[5];
  const float* bih = (const float*)d_in[6];
  const float* bhh = (const float*)d_in[7];
  float* out = (float*)d_out;

  // ws layout (~72 MB; ws ~1 GB per harness poison fill):
  char* ws = (char*)d_ws;
  u16* whT   = (u16*)(ws);                   // [0, 4 MB) Wh^T bf16; aliased by hpb after k_att
  u16* hpb   = (u16*)(ws);                   //   alias
  float* hpp = (float*)(ws + 4194304);       // [4 MB, 68 MB) 8 x h'-partials f32
  float* lgp = (float*)(ws + 71303168);      // 256 KB row-sum partials
  float* srcv = (float*)(ws + 71565312);     // 32 KB
  float* dstv = (float*)(ws + 71598080);     // 32 KB
  (void)ws_size;

  k_zero<<<16, 256, 0, stream>>>(srcv);      // src+dst 64 KB contiguous
  k_wh<<<dim3(128, 4), 256, 0, stream>>>(h, W, a, whT, srcv, dstv);
  k_att<<<256, 512, 0, stream>>>(adj, whT, srcv, dstv, hpp, lgp);
  k_norm<<<2048, 256, 0, stream>>>(hpp, lgp, hpb);
  k_gru<<<dim3(256, 4), 256, 0, stream>>>(hpb, h, wih, whh, bih, bhh, out);
}